// Round 3
// baseline (1342.451 us; speedup 1.0000x reference)
//
#include <hip/hip_runtime.h>

typedef unsigned int uint;
typedef unsigned short ushort;

// Problem constants
#define BB 8
#define SS 4096
#define DD 2048
#define HH 1024
#define EE 8
#define CHUNK 128
#define NCHUNK 32
#define TAU 0.7f

// GEMM tile config
#define BM 128
#define BN 128
#define BK 32          // 4 k-groups of 8
#define KITERS (DD / BK)   // 64

typedef short bf16x8 __attribute__((ext_vector_type(8)));    // 8 bf16 = 4 VGPRs
typedef float f32x16 __attribute__((ext_vector_type(16)));   // 32x32 C frag

// bf16 split helpers: hi = truncate-top-16(x); lo = bf16(x - hi)
__device__ inline uint pack_hi(float a, float b) {
    return (__float_as_uint(a) >> 16) | (__float_as_uint(b) & 0xFFFF0000u);
}
__device__ inline float hi_part(float a) {
    return __uint_as_float(__float_as_uint(a) & 0xFFFF0000u);
}

// ---------------------------------------------------------------------------
// Pre-pass: reorder W1 [D][H] fp32 -> W1hi/W1lo bf16 in MFMA-B-staged layout
// [D/8][H][8] (k-group major, 8 consecutive k per 16B).
// ---------------------------------------------------------------------------
__global__ __launch_bounds__(256) void reorder_w1_kernel(
    const float* __restrict__ W1, ushort* __restrict__ w1hi, ushort* __restrict__ w1lo)
{
    const int kg = blockIdx.x >> 2;                       // 0..255
    const int n  = ((blockIdx.x & 3) << 8) + threadIdx.x; // 0..1023
    float v[8];
#pragma unroll
    for (int j = 0; j < 8; ++j) v[j] = W1[(size_t)(kg * 8 + j) * HH + n];
    uint hi[4], lo[4];
#pragma unroll
    for (int p = 0; p < 4; ++p) {
        const float a = v[2 * p], b = v[2 * p + 1];
        hi[p] = pack_hi(a, b);
        lo[p] = pack_hi(a - hi_part(a), b - hi_part(b));
    }
    const size_t off = (size_t)kg * HH + n;               // uint4 index
    ((uint4*)w1hi)[off] = make_uint4(hi[0], hi[1], hi[2], hi[3]);
    ((uint4*)w1lo)[off] = make_uint4(lo[0], lo[1], lo[2], lo[3]);
}

// ---------------------------------------------------------------------------
// Register-pipelined fused router GEMM.
// Per iter: barrier -> regs->LDS -> barrier -> prefetch next tile into regs
// (plain global->VGPR loads, in flight during MFMA) -> MFMA.
// ---------------------------------------------------------------------------
__global__ __launch_bounds__(256, 3) void router_gemm_kernel(
    const float* __restrict__ x,
    const ushort* __restrict__ w1hi,   // [D/8][H][8] bf16 bits
    const ushort* __restrict__ w1lo,
    const float* __restrict__ b1,
    const float* __restrict__ W2,
    float* __restrict__ chunk_logits)  // [B*NCHUNK][E], pre-zeroed
{
    const int slice = blockIdx.x;      // 0..7
    const int bc    = blockIdx.y;      // 0..255
    const int n0    = slice * BN;

    const int tid  = threadIdx.x;
    const int wave = tid >> 6;
    const int lane = tid & 63;
    const int lm   = lane & 31;
    const int kq   = lane >> 5;
    const int wm   = (wave & 1) * 64;
    const int wn   = (wave >> 1) * 64;

    __shared__ ushort As_hi[4][BM][8];   // 8KB each
    __shared__ ushort As_lo[4][BM][8];
    __shared__ ushort Bs_hi[4][BN][8];
    __shared__ ushort Bs_lo[4][BN][8];
    __shared__ float  W2s[BN][EE];
    __shared__ float  b1s[BN];
    __shared__ float  red[4][EE];

    const float* xrow = x + (size_t)bc * CHUNK * DD;

    // Stage W2 slice + b1 slice (consumed in epilogue; barriers in loop cover it)
    ((float4*)&W2s[0][0])[tid] = ((const float4*)(W2 + (size_t)n0 * EE))[tid];
    if (tid < BN / 4) ((float4*)b1s)[tid] = ((const float4*)(b1 + n0))[tid];

    f32x16 acc[2][2];
#pragma unroll
    for (int i = 0; i < 2; ++i)
#pragma unroll
        for (int j = 0; j < 2; ++j)
#pragma unroll
            for (int r = 0; r < 16; ++r) acc[i][j][r] = 0.0f;

    // A staging coords: thread -> (row, k-half)
    const int am = tid >> 1;          // 0..127
    const int ah = tid & 1;           // 0/1 -> k offset 0/16
    const float*  asrc   = xrow + (size_t)am * DD + ah * 16;
    const ushort* bh_src = w1hi + ((size_t)wave * HH + n0 + lane) * 8;
    const ushort* bl_src = w1lo + ((size_t)wave * HH + n0 + lane) * 8;
    // per-iter stride for B: 4 k-groups * HH * 8 ushorts
    const size_t bstep = (size_t)4 * HH * 8;

    // Prefetch registers
    float4 xv0, xv1, xv2, xv3;
    uint4 bh0, bh1, bl0, bl1;

    // Prologue: load tile 0
    {
        xv0 = ((const float4*)asrc)[0];
        xv1 = ((const float4*)asrc)[1];
        xv2 = ((const float4*)asrc)[2];
        xv3 = ((const float4*)asrc)[3];
        bh0 = *(const uint4*)bh_src;
        bh1 = *(const uint4*)(bh_src + 64 * 8);
        bl0 = *(const uint4*)bl_src;
        bl1 = *(const uint4*)(bl_src + 64 * 8);
    }

    for (int it = 0; it < KITERS; ++it) {
        if (it) __syncthreads();          // previous iter's LDS readers done

        // ---- regs -> LDS: A split to bf16 hi/lo ----
        {
            const float f[16] = {xv0.x, xv0.y, xv0.z, xv0.w, xv1.x, xv1.y, xv1.z, xv1.w,
                                 xv2.x, xv2.y, xv2.z, xv2.w, xv3.x, xv3.y, xv3.z, xv3.w};
            uint hi[8], lo[8];
#pragma unroll
            for (int p = 0; p < 8; ++p) {
                const float a = f[2 * p], b = f[2 * p + 1];
                hi[p] = pack_hi(a, b);
                lo[p] = pack_hi(a - hi_part(a), b - hi_part(b));
            }
            const int kg0 = ah * 2;
            *(uint4*)&As_hi[kg0][am][0]     = make_uint4(hi[0], hi[1], hi[2], hi[3]);
            *(uint4*)&As_hi[kg0 + 1][am][0] = make_uint4(hi[4], hi[5], hi[6], hi[7]);
            *(uint4*)&As_lo[kg0][am][0]     = make_uint4(lo[0], lo[1], lo[2], lo[3]);
            *(uint4*)&As_lo[kg0 + 1][am][0] = make_uint4(lo[4], lo[5], lo[6], lo[7]);
        }
        // ---- regs -> LDS: B (already bf16) ----
        *(uint4*)&Bs_hi[wave][lane][0]      = bh0;
        *(uint4*)&Bs_hi[wave][lane + 64][0] = bh1;
        *(uint4*)&Bs_lo[wave][lane][0]      = bl0;
        *(uint4*)&Bs_lo[wave][lane + 64][0] = bl1;

        __syncthreads();                  // LDS ready

        // ---- prefetch next tile into registers (in flight during MFMA) ----
        {
            const int nx = (it + 1 < KITERS) ? it + 1 : it;   // clamp: last iter reloads, harmless
            const float* s = asrc + nx * BK;
            xv0 = ((const float4*)s)[0];
            xv1 = ((const float4*)s)[1];
            xv2 = ((const float4*)s)[2];
            xv3 = ((const float4*)s)[3];
            const ushort* ph = bh_src + (size_t)nx * bstep;
            const ushort* pl = bl_src + (size_t)nx * bstep;
            bh0 = *(const uint4*)ph;
            bh1 = *(const uint4*)(ph + 64 * 8);
            bl0 = *(const uint4*)pl;
            bl1 = *(const uint4*)(pl + 64 * 8);
        }

        // ---- MFMA: 2 kg-steps x 2x2 tiles x 3 split terms ----
#pragma unroll
        for (int s2 = 0; s2 < 2; ++s2) {
            const int kg = 2 * s2 + kq;
            bf16x8 a_h[2], a_l[2], b_h[2], b_l[2];
#pragma unroll
            for (int i = 0; i < 2; ++i) {
                a_h[i] = *(const bf16x8*)&As_hi[kg][wm + i * 32 + lm][0];
                a_l[i] = *(const bf16x8*)&As_lo[kg][wm + i * 32 + lm][0];
            }
#pragma unroll
            for (int j = 0; j < 2; ++j) {
                b_h[j] = *(const bf16x8*)&Bs_hi[kg][wn + j * 32 + lm][0];
                b_l[j] = *(const bf16x8*)&Bs_lo[kg][wn + j * 32 + lm][0];
            }
#pragma unroll
            for (int i = 0; i < 2; ++i)
#pragma unroll
                for (int j = 0; j < 2; ++j) {
                    acc[i][j] = __builtin_amdgcn_mfma_f32_32x32x16_bf16(
                        a_l[i], b_h[j], acc[i][j], 0, 0, 0);
                    acc[i][j] = __builtin_amdgcn_mfma_f32_32x32x16_bf16(
                        a_h[i], b_l[j], acc[i][j], 0, 0, 0);
                    acc[i][j] = __builtin_amdgcn_mfma_f32_32x32x16_bf16(
                        a_h[i], b_h[j], acc[i][j], 0, 0, 0);
                }
        }
    }

    // ---- Epilogue: relu + second GEMM + chunk partial sum ----
    float part[EE];
#pragma unroll
    for (int e = 0; e < EE; ++e) part[e] = 0.0f;

#pragma unroll
    for (int j = 0; j < 2; ++j) {
        const int hl = wn + j * 32 + lm;
        const float bias = b1s[hl];
        float w2r[EE];
#pragma unroll
        for (int e = 0; e < EE; ++e) w2r[e] = W2s[hl][e];
#pragma unroll
        for (int i = 0; i < 2; ++i)
#pragma unroll
            for (int r = 0; r < 16; ++r) {
                const float hv = fmaxf(acc[i][j][r] + bias, 0.0f);
#pragma unroll
                for (int e = 0; e < EE; ++e) part[e] = fmaf(hv, w2r[e], part[e]);
            }
    }

#pragma unroll
    for (int off = 32; off >= 1; off >>= 1)
#pragma unroll
        for (int e = 0; e < EE; ++e) part[e] += __shfl_down(part[e], off, 64);

    if (lane == 0)
#pragma unroll
        for (int e = 0; e < EE; ++e) red[wave][e] = part[e];
    __syncthreads();
    if (tid < EE) {
        const float s = red[0][tid] + red[1][tid] + red[2][tid] + red[3][tid];
        atomicAdd(&chunk_logits[(size_t)bc * EE + tid], s * (1.0f / CHUNK));
    }
}

// ---------------------------------------------------------------------------
// Hysteresis scan: LDS-preload all chunk logits, per-batch serial scan.
// ---------------------------------------------------------------------------
__global__ void hysteresis_kernel(const float* __restrict__ chunk_logits,
                                  const float* __restrict__ b2,
                                  int* __restrict__ eidx_ws,
                                  float* __restrict__ out_idx)
{
    __shared__ float cls[BB * NCHUNK * EE];
    const int tid = threadIdx.x;              // 0..63
#pragma unroll
    for (int i = 0; i < 8; ++i)
        ((float4*)cls)[tid + i * 64] = ((const float4*)chunk_logits)[tid + i * 64];
    __syncthreads();

    const int b = tid;
    if (b >= BB) return;
    float b2r[EE];
#pragma unroll
    for (int e = 0; e < EE; ++e) b2r[e] = b2[e];

    const float* cl = cls + b * NCHUNK * EE;
    int prev = 0;
    for (int c = 0; c < NCHUNK; ++c) {
        float v[EE];
        float best = -3.4e38f;
        int ce = 0;
#pragma unroll
        for (int e = 0; e < EE; ++e) {
            const float lv = cl[c * EE + e] + b2r[e];
            v[e] = lv;
            if (lv > best) { best = lv; ce = e; }
        }
        if (c == 0) prev = ce;
        else if (best - v[prev] > TAU) prev = ce;
        eidx_ws[b * NCHUNK + c] = prev;
        out_idx[b * NCHUNK + c] = (float)prev;
    }
}

// ---------------------------------------------------------------------------
// One-hot routing weights.
// ---------------------------------------------------------------------------
__global__ __launch_bounds__(256) void onehot_kernel(const int* __restrict__ eidx,
                                                     float* __restrict__ out)
{
    const int tok = blockIdx.x * blockDim.x + threadIdx.x;
    if (tok >= BB * SS) return;
    const int b = tok / SS;
    const int s = tok - b * SS;
    const int idx = eidx[b * NCHUNK + (s / CHUNK)];
    float vals[EE];
#pragma unroll
    for (int e = 0; e < EE; ++e) vals[e] = (e == idx) ? 1.0f : 0.0f;
    float4* o = (float4*)(out + (size_t)tok * EE);
    o[0] = make_float4(vals[0], vals[1], vals[2], vals[3]);
    o[1] = make_float4(vals[4], vals[5], vals[6], vals[7]);
}

// ---------------------------------------------------------------------------
extern "C" void kernel_launch(void* const* d_in, const int* in_sizes, int n_in,
                              void* d_out, int out_size, void* d_ws, size_t ws_size,
                              hipStream_t stream)
{
    const float* x  = (const float*)d_in[0];
    const float* W1 = (const float*)d_in[1];
    const float* b1 = (const float*)d_in[2];
    const float* W2 = (const float*)d_in[3];
    const float* b2 = (const float*)d_in[4];
    float* out = (float*)d_out;

    // ws layout: W1hi (4MB) | W1lo (4MB) | chunk_logits (8KB) | eidx (1KB)
    ushort* w1hi         = (ushort*)d_ws;
    ushort* w1lo         = (ushort*)((char*)d_ws + (size_t)4 * 1024 * 1024);
    float*  chunk_logits = (float*)((char*)d_ws + (size_t)8 * 1024 * 1024);
    int*    eidx         = (int*)((char*)d_ws + (size_t)8 * 1024 * 1024 + 8192);

    hipMemsetAsync(chunk_logits, 0, BB * NCHUNK * EE * sizeof(float), stream);

    reorder_w1_kernel<<<1024, 256, 0, stream>>>(W1, w1hi, w1lo);

    dim3 grid(HH / BN, BB * NCHUNK);   // (8, 256)
    router_gemm_kernel<<<grid, 256, 0, stream>>>(x, w1hi, w1lo, b1, W2, chunk_logits);

    hysteresis_kernel<<<1, 64, 0, stream>>>(chunk_logits, b2, eidx,
                                            out + (size_t)BB * SS * EE);

    onehot_kernel<<<(BB * SS + 255) / 256, 256, 0, stream>>>(eidx, out);
}